// Round 5
// baseline (1027.249 us; speedup 1.0000x reference)
//
#include <hip/hip_runtime.h>

#define N_NODES 50000
#define N_EDGES 1600000

typedef _Float16 h8 __attribute__((ext_vector_type(8)));
typedef float f4 __attribute__((ext_vector_type(4)));

__device__ inline h8 ld_h8(const _Float16* p) { return *(const h8*)p; }

__device__ inline h8 cvt2h8(f4 a, f4 b) {
    h8 r;
    r[0] = (_Float16)a[0]; r[1] = (_Float16)a[1]; r[2] = (_Float16)a[2]; r[3] = (_Float16)a[3];
    r[4] = (_Float16)b[0]; r[5] = (_Float16)b[1]; r[6] = (_Float16)b[2]; r[7] = (_Float16)b[3];
    return r;
}

// ---------------- prep kernels ----------------
// Wm1/Wm2 are emitted as the final LDS image for the msg kernel:
//   img[(ks*128 + o)*32 + (q ^ ((o>>1)&3))*8 + j] = W[(ks*32 + q*8 + j)*128 + o]
// XOR chunk swizzle -> uniform 2-way LDS bank access on ds_read_b128 (free).

__global__ void prep_weights(const float* __restrict__ Wm1, const float* __restrict__ Wa1,
                             const float* __restrict__ Wm2, const float* __restrict__ Wa2,
                             const float* __restrict__ W1,
                             _Float16* __restrict__ Wm1t, _Float16* __restrict__ Wa1t,
                             _Float16* __restrict__ Wm2t, _Float16* __restrict__ Wa2t,
                             _Float16* __restrict__ W1t)
{
    int i = blockIdx.x * 256 + threadIdx.x;
    if (i < 12288) {                       // Wm1: 128*96, msg-swizzled image
        int o = i / 96, k = i % 96;
        int ks = k >> 5, q = (k >> 3) & 3, j = k & 7;
        int c = q ^ ((o >> 1) & 3);
        Wm1t[(ks * 128 + o) * 32 + c * 8 + j] = (_Float16)Wm1[k * 128 + o];
    } else if (i < 36864) {                // + 128*192 (Wa1, unchanged layout)
        int jj = i - 12288; int o = jj / 192, k = jj % 192;
        Wa1t[o * 200 + k] = (_Float16)Wa1[k * 128 + o];
    } else if (i < 57344) {                // + 128*160 (Wm2, msg-swizzled image)
        int jj = i - 36864; int o = jj / 160, k = jj % 160;
        int ks = k >> 5, q = (k >> 3) & 3, j = k & 7;
        int c = q ^ ((o >> 1) & 3);
        Wm2t[(ks * 128 + o) * 32 + c * 8 + j] = (_Float16)Wm2[k * 128 + o];
    } else if (i < 90112) {                // + 128*256 (Wa2, unchanged)
        int jj = i - 57344; int o = jj >> 8, k = jj & 255;
        Wa2t[(o << 8) + k] = (_Float16)Wa2[k * 128 + o];
    } else if (i < 122880) {               // + 128*256 (W1, unchanged)
        int jj = i - 90112; int o = jj >> 8, k = jj & 255;
        W1t[(o << 8) + k] = (_Float16)W1[k * 128 + o];
    }
}

__global__ void cvt_nfeats(const float* __restrict__ nf, _Float16* __restrict__ nf16)
{
    int i = blockIdx.x * 256 + threadIdx.x;   // exactly N*64 = 3.2M threads
    nf16[i] = (_Float16)nf[i];
}

// ---------------- counting sort of edges by dst ----------------

__global__ void hist_kernel(const int* __restrict__ dst, int* __restrict__ cnt)
{
    int e = blockIdx.x * 256 + threadIdx.x;   // exactly E threads
    atomicAdd(cnt + dst[e], 1);
}

__global__ void scan1_kernel(const int* __restrict__ cnt, int* __restrict__ tmp,
                             int* __restrict__ bsum)
{
    __shared__ int sh[256];
    int t = threadIdx.x, i = blockIdx.x * 256 + t;
    int v = (i < N_NODES) ? cnt[i] : 0;
    sh[t] = v; __syncthreads();
    for (int off = 1; off < 256; off <<= 1) {
        int x = (t >= off) ? sh[t - off] : 0;
        __syncthreads();
        sh[t] += x;
        __syncthreads();
    }
    if (i < N_NODES) tmp[i] = sh[t];
    if (t == 255) bsum[blockIdx.x] = sh[255];
}

__global__ void scan2_kernel(const int* __restrict__ bsum, int* __restrict__ bbase)
{
    __shared__ int sh[256];
    int t = threadIdx.x;
    int v = (t < 196) ? bsum[t] : 0;
    sh[t] = v; __syncthreads();
    for (int off = 1; off < 256; off <<= 1) {
        int x = (t >= off) ? sh[t - off] : 0;
        __syncthreads();
        sh[t] += x;
        __syncthreads();
    }
    if (t < 196) bbase[t] = sh[t] - v;   // exclusive
}

__global__ void scan3_kernel(const int* __restrict__ cnt, const int* __restrict__ tmp,
                             const int* __restrict__ bbase, int* __restrict__ cursor)
{
    int t = threadIdx.x, b = blockIdx.x, i = b * 256 + t;
    if (i < N_NODES) cursor[i] = tmp[i] - cnt[i] + bbase[b];
}

// scatter materializes, in dst-sorted slot order:
//   pairs[pos] = (edge_id, src_node)
//   dsts[pos]  = dst_node
//   efs[pos]   = fp16(efeats[e])  (EF variant) -- msg kernels then stream efeats
//                coalesced by slot instead of gathering 128-B fp32 rows from HBM.
__global__ void scatter_kernel(const int* __restrict__ src, const int* __restrict__ dst,
                               int* __restrict__ cursor,
                               int2* __restrict__ pairs, int* __restrict__ dsts)
{
    int e = blockIdx.x * 256 + threadIdx.x;   // exactly E threads
    int d = dst[e];
    int pos = atomicAdd(cursor + d, 1);
    pairs[pos] = make_int2(e, src[e]);
    dsts[pos] = d;
}

__global__ void scatter_kernel_ef(const int* __restrict__ src, const int* __restrict__ dst,
                                  const float* __restrict__ efeats,
                                  int* __restrict__ cursor,
                                  int2* __restrict__ pairs, int* __restrict__ dsts,
                                  _Float16* __restrict__ efs)
{
    int e = blockIdx.x * 256 + threadIdx.x;   // exactly E threads
    int d = dst[e];
    const float* er = efeats + (size_t)e * 32;   // coalesced 128-B read
    f4 v0 = *(const f4*)(er + 0),  v1 = *(const f4*)(er + 4);
    f4 v2 = *(const f4*)(er + 8),  v3 = *(const f4*)(er + 12);
    f4 v4 = *(const f4*)(er + 16), v5 = *(const f4*)(er + 20);
    f4 v6 = *(const f4*)(er + 24), v7 = *(const f4*)(er + 28);
    int pos = atomicAdd(cursor + d, 1);
    pairs[pos] = make_int2(e, src[e]);
    dsts[pos] = d;
    _Float16* ew = efs + (size_t)pos * 32;       // scattered 64-B row (full line halves)
    *(h8*)(ew + 0)  = cvt2h8(v0, v1);
    *(h8*)(ew + 8)  = cvt2h8(v2, v3);
    *(h8*)(ew + 16) = cvt2h8(v4, v5);
    *(h8*)(ew + 24) = cvt2h8(v6, v7);
}

// ---------------- edge message kernel ----------------
// Block = 128 dst-sorted edge slots, 4 waves x 32 slots. All A-side inputs
// (ntab rows, efeats) prefetched into registers BEFORE B staging. LDS = B image
// only (aliased post-barrier by an 8-row per-wave scratch for the mixed reduce).
// Mixed-path scan is fully unrolled; dst values come from the already-loaded
// dv registers via compile-time shuffles (no serial uniform-load chain).
template<int KSRC_H, int MINW, bool EF16>
__launch_bounds__(256, MINW)
__global__ void msg_kernel_sorted(const _Float16* __restrict__ ntab,
                                  const float* __restrict__ efeats,
                                  const _Float16* __restrict__ efs,
                                  const int2* __restrict__ pairs,
                                  const int* __restrict__ dsts,
                                  const _Float16* __restrict__ Wt,
                                  const float* __restrict__ bias,
                                  float* __restrict__ sacc)
{
    constexpr int EFSTEP = KSRC_H / 32;
    constexpr int KSTEPS = EFSTEP + 1;
    constexpr int BH = (KSRC_H + 32) * 128;              // fp16 elems
    constexpr int BBYTES = BH * 2;
    constexpr int SCRBYTES = 4 * 8 * 132 * 4;            // 16896 (8-row half-tile)
    constexpr int LDSBYTES = BBYTES > SCRBYTES ? BBYTES : SCRBYTES;  // L1 24576, L2 40960
    __shared__ __align__(16) char smem[LDSBYTES];
    _Float16* Bsh = (_Float16*)smem;

    const int tid = threadIdx.x;
    const int wave = tid >> 6, lane = tid & 63;
    const int q = lane >> 4, l15 = lane & 15;
    const int wbase = blockIdx.x * 128 + wave * 32;

    // ---- early independent loads (overlap with B staging) ----
    const int2 p0 = pairs[wbase + l15];
    const int2 p1 = pairs[wbase + 16 + l15];
    const int4 dv0 = *(const int4*)(dsts + wbase + q * 4);
    const int4 dv1 = *(const int4*)(dsts + wbase + 16 + q * 4);
    float bv[8];
#pragma unroll
    for (int nt = 0; nt < 8; nt++) bv[nt] = bias[nt * 16 + l15];

    const _Float16* r0 = ntab + (size_t)p0.y * KSRC_H + q * 8;
    const _Float16* r1 = ntab + (size_t)p1.y * KSRC_H + q * 8;
    h8 aA[EFSTEP], aB[EFSTEP];
#pragma unroll
    for (int ks = 0; ks < EFSTEP; ks++) {
        aA[ks] = ld_h8(r0 + ks * 32);
        aB[ks] = ld_h8(r1 + ks * 32);
    }
    h8 ef0h, ef1h;
    f4 e0a, e0b, e1a, e1b;
    if constexpr (EF16) {
        ef0h = ld_h8(efs + (size_t)(wbase + l15) * 32 + q * 8);        // coalesced by slot
        ef1h = ld_h8(efs + (size_t)(wbase + 16 + l15) * 32 + q * 8);
    } else {
        const float* ep0 = efeats + (size_t)p0.x * 32 + q * 8;
        const float* ep1 = efeats + (size_t)p1.x * 32 + q * 8;
        e0a = *(const f4*)ep0; e0b = *(const f4*)(ep0 + 4);
        e1a = *(const f4*)ep1; e1b = *(const f4*)(ep1 + 4);
    }

    // ---- stage B (linear copy; image pre-swizzled on host side) ----
    {
        const uint4* s4 = (const uint4*)Wt;
        uint4* d4 = (uint4*)smem;
        constexpr int n4 = BH / 8;
        for (int i = tid; i < n4; i += 256) d4[i] = s4[i];
    }
    __syncthreads();

    f4 acc[2][8];
#pragma unroll
    for (int t = 0; t < 2; t++)
#pragma unroll
        for (int nt = 0; nt < 8; nt++) acc[t][nt] = (f4){0.f, 0.f, 0.f, 0.f};

    const _Float16* bp = Bsh + l15 * 32 + ((q ^ ((l15 >> 1) & 3)) << 3);
#pragma unroll
    for (int ks = 0; ks < KSTEPS; ks++) {
        h8 a0, a1;
        if (ks < EFSTEP) {
            a0 = aA[ks]; a1 = aB[ks];
        } else {
            if constexpr (EF16) { a0 = ef0h; a1 = ef1h; }
            else { a0 = cvt2h8(e0a, e0b); a1 = cvt2h8(e1a, e1b); }
        }
#pragma unroll
        for (int nt = 0; nt < 8; nt++) {
            h8 b = ld_h8(bp + ks * 4096 + nt * 512);
            acc[0][nt] = __builtin_amdgcn_mfma_f32_16x16x32_f16(a0, b, acc[0][nt], 0, 0, 0);
            acc[1][nt] = __builtin_amdgcn_mfma_f32_16x16x32_f16(a1, b, acc[1][nt], 0, 0, 0);
        }
    }

    __syncthreads();   // B image dead everywhere; smem becomes per-wave scratch

    float* wsch = (float*)smem + wave * 1056;   // 8*132 floats per wave

    const int df0 = __shfl(dv0.x, 0, 64);       // dst of row wbase+0
    const int dl0 = __shfl(dv0.w, 48, 64);      // dst of row wbase+15
    const int df1 = __shfl(dv1.x, 0, 64);       // dst of row wbase+16
    const int dl1 = __shfl(dv1.w, 48, 64);      // dst of row wbase+31

    auto unif16 = [&](const f4 (&a)[8], int d) {
        float sv[8];
#pragma unroll
        for (int nt = 0; nt < 8; nt++) {
            float s = fmaxf(a[nt][0] + bv[nt], 0.f) + fmaxf(a[nt][1] + bv[nt], 0.f)
                    + fmaxf(a[nt][2] + bv[nt], 0.f) + fmaxf(a[nt][3] + bv[nt], 0.f);
            s += __shfl_xor(s, 16, 64);
            s += __shfl_xor(s, 32, 64);
            sv[nt] = s;
        }
#pragma unroll
        for (int i = 0; i < 2; i++) {
            float x = (q == 0) ? sv[i*4] : (q == 1) ? sv[i*4+1] : (q == 2) ? sv[i*4+2] : sv[i*4+3];
            atomicAdd(sacc + (size_t)d * 128 + i * 64 + lane, x);
        }
    };

    // mixed 16-row group: two 8-row spills into wave scratch; fully-unrolled
    // column-serial scan with shuffle-sourced dst values (wave-uniform branches).
    auto scan16 = [&](const f4 (&a)[8], const int4 dv, int dfirst) {
        int dp = dfirst;
        float s0 = 0.f, s1 = 0.f;
#pragma unroll
        for (int h = 0; h < 2; h++) {
            if ((q >> 1) == h) {                 // lanes owning rows h*8..h*8+7
                const int rloc = (q & 1) * 4;
#pragma unroll
                for (int nt = 0; nt < 8; nt++)
#pragma unroll
                    for (int r = 0; r < 4; r++)
                        wsch[(rloc + r) * 132 + nt * 16 + l15] = fmaxf(a[nt][r] + bv[nt], 0.f);
            }
            asm volatile("s_waitcnt lgkmcnt(0)" ::: "memory");
#pragma unroll
            for (int rr = 0; rr < 8; rr++) {
                const int rg = h * 8 + rr;
                const int sl = (rg >> 2) << 4;
                const int c = rg & 3;
                const int d = (c == 0) ? __shfl(dv.x, sl, 64)
                            : (c == 1) ? __shfl(dv.y, sl, 64)
                            : (c == 2) ? __shfl(dv.z, sl, 64)
                            :            __shfl(dv.w, sl, 64);
                const float v0 = wsch[rr * 132 + lane];
                const float v1 = wsch[rr * 132 + 64 + lane];
                if (d != dp) {                   // wave-uniform branch
                    atomicAdd(sacc + (size_t)dp * 128 + lane, s0);
                    atomicAdd(sacc + (size_t)dp * 128 + 64 + lane, s1);
                    s0 = v0; s1 = v1; dp = d;
                } else {
                    s0 += v0; s1 += v1;
                }
            }
        }
        atomicAdd(sacc + (size_t)dp * 128 + lane, s0);
        atomicAdd(sacc + (size_t)dp * 128 + 64 + lane, s1);
    };

    if (df0 == dl1) {
        // whole 32-row wave segment is one dst (sorted -> uniform)
        float sv[8];
#pragma unroll
        for (int nt = 0; nt < 8; nt++) {
            float s = fmaxf(acc[0][nt][0] + bv[nt], 0.f) + fmaxf(acc[0][nt][1] + bv[nt], 0.f)
                    + fmaxf(acc[0][nt][2] + bv[nt], 0.f) + fmaxf(acc[0][nt][3] + bv[nt], 0.f)
                    + fmaxf(acc[1][nt][0] + bv[nt], 0.f) + fmaxf(acc[1][nt][1] + bv[nt], 0.f)
                    + fmaxf(acc[1][nt][2] + bv[nt], 0.f) + fmaxf(acc[1][nt][3] + bv[nt], 0.f);
            s += __shfl_xor(s, 16, 64);
            s += __shfl_xor(s, 32, 64);
            sv[nt] = s;
        }
#pragma unroll
        for (int i = 0; i < 2; i++) {
            float x = (q == 0) ? sv[i*4] : (q == 1) ? sv[i*4+1] : (q == 2) ? sv[i*4+2] : sv[i*4+3];
            atomicAdd(sacc + (size_t)df0 * 128 + i * 64 + lane, x);
        }
    } else {
        if (df0 == dl0) unif16(acc[0], df0); else scan16(acc[0], dv0, df0);
        if (df1 == dl1) unif16(acc[1], df1); else scan16(acc[1], dv1, df1);
    }
}

// ---------------- node apply kernel (unchanged) ----------------
template<int KSRC_H, bool SWIZ, int KPAD>
__launch_bounds__(256)
__global__ void apply_kernel(const _Float16* __restrict__ ntab,
                             const float* __restrict__ sacc,
                             const int* __restrict__ cnt,
                             const _Float16* __restrict__ Wt,
                             const float* __restrict__ bias,
                             _Float16* __restrict__ outtab)
{
    constexpr int KSTEPS = (KSRC_H + 128) / 32;
    __shared__ __align__(16) _Float16 Bsh[128 * KPAD];

    const int tid = threadIdx.x;
    if (SWIZ) {
        const uint4* s4 = (const uint4*)Wt;
        uint4* d4 = (uint4*)Bsh;
        for (int i = tid; i < 4096; i += 256) {
            int n = i >> 5, c = i & 31;
            d4[(n << 5) | (c ^ (n & 31))] = s4[i];
        }
    } else {
        const uint4* s4 = (const uint4*)Wt;
        uint4* d4 = (uint4*)Bsh;
        constexpr int n4 = 128 * KPAD / 8;
        for (int i = tid; i < n4; i += 256) d4[i] = s4[i];
    }
    __syncthreads();

    const int wave = tid >> 6, lane = tid & 63;
    const int q = lane >> 4, l15 = lane & 15;
    const int nbase = blockIdx.x * 128 + wave * 32;

    const int n0 = nbase + l15, n1 = nbase + 16 + l15;
    const int n0c = min(n0, N_NODES - 1), n1c = min(n1, N_NODES - 1);
    const _Float16* r0 = ntab + (size_t)n0c * KSRC_H;
    const _Float16* r1 = ntab + (size_t)n1c * KSRC_H;
    const float rcp0 = 1.0f / fmaxf((float)cnt[n0c], 1.0f);
    const float rcp1 = 1.0f / fmaxf((float)cnt[n1c], 1.0f);

    f4 acc[2][8];
#pragma unroll
    for (int t = 0; t < 2; t++)
#pragma unroll
        for (int nt = 0; nt < 8; nt++) acc[t][nt] = (f4){0.f, 0.f, 0.f, 0.f};

#pragma unroll
    for (int ks = 0; ks < KSTEPS; ks++) {
        h8 a0, a1;
        if (ks < KSRC_H / 32) {
            a0 = ld_h8(r0 + ks * 32 + q * 8);
            a1 = ld_h8(r1 + ks * 32 + q * 8);
        } else {
            const int kk = ks * 32 - KSRC_H + q * 8;
            const float* p0 = sacc + (size_t)n0c * 128 + kk;
            const float* p1 = sacc + (size_t)n1c * 128 + kk;
            f4 u0 = *(const f4*)p0 * rcp0, v0 = *(const f4*)(p0 + 4) * rcp0;
            f4 u1 = *(const f4*)p1 * rcp1, v1 = *(const f4*)(p1 + 4) * rcp1;
            a0 = cvt2h8(u0, v0);
            a1 = cvt2h8(u1, v1);
        }
#pragma unroll
        for (int nt = 0; nt < 8; nt++) {
            h8 b;
            if (SWIZ) {
                const int nrow = nt * 16 + l15;
                const int chunk = ((ks << 2) | q) ^ (nrow & 31);
                b = ld_h8(Bsh + (((nrow << 5) | chunk) << 3));
            } else {
                b = ld_h8(&Bsh[(nt * 16 + l15) * KPAD + ks * 32 + q * 8]);
            }
            acc[0][nt] = __builtin_amdgcn_mfma_f32_16x16x32_f16(a0, b, acc[0][nt], 0, 0, 0);
            acc[1][nt] = __builtin_amdgcn_mfma_f32_16x16x32_f16(a1, b, acc[1][nt], 0, 0, 0);
        }
    }

#pragma unroll
    for (int nt = 0; nt < 8; nt++) {
        const int col = nt * 16 + l15;
        const float bv = bias[col];
#pragma unroll
        for (int t = 0; t < 2; t++)
#pragma unroll
            for (int r = 0; r < 4; r++) {
                const int node = nbase + t * 16 + q * 4 + r;
                if (node < N_NODES) {
                    float v = fmaxf(acc[t][nt][r] + bv, 0.f);
                    outtab[(size_t)node * 128 + col] = (_Float16)v;
                }
            }
    }
}

// ---------------- per-node predictor halves (unchanged) ----------------
__launch_bounds__(256)
__global__ void node_pq_kernel(const _Float16* __restrict__ h2,
                               const _Float16* __restrict__ W1t,  // [128 out][256 k] image
                               const float* __restrict__ b1,
                               _Float16* __restrict__ P,
                               float* __restrict__ Q)
{
    __shared__ __align__(16) _Float16 Bsh[128 * 256];

    const int tid = threadIdx.x;
    {
        const uint4* s4 = (const uint4*)W1t;
        uint4* d4 = (uint4*)Bsh;
        for (int i = tid; i < 4096; i += 256) {
            int n = i >> 5, c = i & 31;
            d4[(n << 5) | (c ^ (n & 31))] = s4[i];
        }
    }
    __syncthreads();

    const int wave = tid >> 6, lane = tid & 63;
    const int q = lane >> 4, l15 = lane & 15;
    const int nbase = blockIdx.x * 128 + wave * 32;

    const int n0 = nbase + l15, n1 = nbase + 16 + l15;
    const int n0c = min(n0, N_NODES - 1), n1c = min(n1, N_NODES - 1);
    const _Float16* r0 = h2 + (size_t)n0c * 128;
    const _Float16* r1 = h2 + (size_t)n1c * 128;

    f4 accP[2][8], accQ[2][8];
#pragma unroll
    for (int t = 0; t < 2; t++)
#pragma unroll
        for (int nt = 0; nt < 8; nt++) {
            accP[t][nt] = (f4){0.f, 0.f, 0.f, 0.f};
            accQ[t][nt] = (f4){0.f, 0.f, 0.f, 0.f};
        }

#pragma unroll
    for (int ks = 0; ks < 4; ks++) {
        h8 a0 = ld_h8(r0 + ks * 32 + q * 8);
        h8 a1 = ld_h8(r1 + ks * 32 + q * 8);
#pragma unroll
        for (int nt = 0; nt < 8; nt++) {
            const int nrow = nt * 16 + l15;
            const int cP = ((ks << 2) | q) ^ (nrow & 31);
            h8 bP = ld_h8(Bsh + (((nrow << 5) | cP) << 3));
            accP[0][nt] = __builtin_amdgcn_mfma_f32_16x16x32_f16(a0, bP, accP[0][nt], 0, 0, 0);
            accP[1][nt] = __builtin_amdgcn_mfma_f32_16x16x32_f16(a1, bP, accP[1][nt], 0, 0, 0);
            const int cQ = (((ks + 4) << 2) | q) ^ (nrow & 31);
            h8 bQ = ld_h8(Bsh + (((nrow << 5) | cQ) << 3));
            accQ[0][nt] = __builtin_amdgcn_mfma_f32_16x16x32_f16(a0, bQ, accQ[0][nt], 0, 0, 0);
            accQ[1][nt] = __builtin_amdgcn_mfma_f32_16x16x32_f16(a1, bQ, accQ[1][nt], 0, 0, 0);
        }
    }

#pragma unroll
    for (int nt = 0; nt < 8; nt++) {
        const int col = nt * 16 + l15;
        const float bq = b1[col];
#pragma unroll
        for (int t = 0; t < 2; t++)
#pragma unroll
            for (int r = 0; r < 4; r++) {
                const int node = nbase + t * 16 + q * 4 + r;
                if (node < N_NODES) {
                    P[(size_t)node * 128 + col] = (_Float16)accP[t][nt][r];
                    Q[(size_t)node * 128 + col] = accQ[t][nt][r] + bq;
                }
            }
    }
}

// ---------------- elementwise edge predictor (unchanged) ----------------
__launch_bounds__(256, 4)
__global__ void pred_elem_kernel(const _Float16* __restrict__ P,
                                 const float* __restrict__ Q,
                                 const int2* __restrict__ pairs,
                                 const int* __restrict__ dsts,
                                 const float* __restrict__ W2,   // [128][2]
                                 const float* __restrict__ b2,
                                 float* __restrict__ out)
{
    __shared__ __align__(16) float w20sh[128];
    __shared__ __align__(16) float w21sh[128];

    const int tid = threadIdx.x;
    if (tid < 128) {
        w20sh[tid] = W2[tid * 2 + 0];
        w21sh[tid] = W2[tid * 2 + 1];
    }
    __syncthreads();

    const int slot = blockIdx.x * 256 + tid;   // grid covers E exactly
    const int2 pr = pairs[slot];
    const int d = dsts[slot];
    const _Float16* prow = P + (size_t)pr.y * 128;
    const float* qrow = Q + (size_t)d * 128;

    float o0 = 0.f, o1 = 0.f;
#pragma unroll
    for (int c = 0; c < 4; c++) {              // 32 elements per chunk
        h8 pv[4];
#pragma unroll
        for (int i = 0; i < 4; i++) pv[i] = ld_h8(prow + c * 32 + i * 8);
        f4 qv[8];
#pragma unroll
        for (int i = 0; i < 8; i++) qv[i] = *(const f4*)(qrow + c * 32 + i * 4);
#pragma unroll
        for (int i = 0; i < 8; i++) {
            const f4 w0 = *(const f4*)(w20sh + c * 32 + i * 4);   // uniform -> broadcast
            const f4 w1 = *(const f4*)(w21sh + c * 32 + i * 4);
#pragma unroll
            for (int j = 0; j < 4; j++) {
                const float pvf = (float)pv[i >> 1][(i & 1) * 4 + j];
                const float y = fmaxf(pvf + qv[i][j], 0.f);
                o0 += y * w0[j];
                o1 += y * w1[j];
            }
        }
    }

    out[(size_t)pr.x * 2 + 0] = o0 + b2[0];
    out[(size_t)pr.x * 2 + 1] = o1 + b2[1];
}

// ---------------- legacy predictor (fallback when ws too small) ----------------
__launch_bounds__(256)
__global__ void pred_kernel(const _Float16* __restrict__ h2,
                            const int* __restrict__ src,
                            const int* __restrict__ dst,
                            const _Float16* __restrict__ W1t,  // [128][256] unpadded
                            const float* __restrict__ b1,
                            const float* __restrict__ W2,      // [128][2] fp32
                            const float* __restrict__ b2,
                            float* __restrict__ out)
{
    __shared__ __align__(16) _Float16 Bsh[128 * 256];

    const int tid = threadIdx.x;
    {
        const uint4* s4 = (const uint4*)W1t;
        uint4* d4 = (uint4*)Bsh;
        for (int i = tid; i < 4096; i += 256) {
            int n = i >> 5, c = i & 31;
            d4[(n << 5) | (c ^ (n & 31))] = s4[i];
        }
    }
    __syncthreads();

    const int wave = tid >> 6, lane = tid & 63;
    const int q = lane >> 4, l15 = lane & 15;
    const int ebase = blockIdx.x * 128 + wave * 32;

    const int e0 = ebase + l15, e1 = ebase + 16 + l15;
    const _Float16* rs0 = h2 + (size_t)src[e0] * 128;
    const _Float16* rd0 = h2 + (size_t)dst[e0] * 128;
    const _Float16* rs1 = h2 + (size_t)src[e1] * 128;
    const _Float16* rd1 = h2 + (size_t)dst[e1] * 128;

    f4 acc[2][8];
#pragma unroll
    for (int t = 0; t < 2; t++)
#pragma unroll
        for (int nt = 0; nt < 8; nt++) acc[t][nt] = (f4){0.f, 0.f, 0.f, 0.f};

#pragma unroll
    for (int ks = 0; ks < 8; ks++) {
        h8 a0, a1;
        if (ks < 4) {
            a0 = ld_h8(rs0 + ks * 32 + q * 8);
            a1 = ld_h8(rs1 + ks * 32 + q * 8);
        } else {
            a0 = ld_h8(rd0 + (ks - 4) * 32 + q * 8);
            a1 = ld_h8(rd1 + (ks - 4) * 32 + q * 8);
        }
#pragma unroll
        for (int nt = 0; nt < 8; nt++) {
            const int nrow = nt * 16 + l15;
            const int chunk = ((ks << 2) | q) ^ (nrow & 31);
            h8 b = ld_h8(Bsh + (((nrow << 5) | chunk) << 3));
            acc[0][nt] = __builtin_amdgcn_mfma_f32_16x16x32_f16(a0, b, acc[0][nt], 0, 0, 0);
            acc[1][nt] = __builtin_amdgcn_mfma_f32_16x16x32_f16(a1, b, acc[1][nt], 0, 0, 0);
        }
    }

    float o[2][4][2];
#pragma unroll
    for (int t = 0; t < 2; t++)
#pragma unroll
        for (int r = 0; r < 4; r++) { o[t][r][0] = 0.f; o[t][r][1] = 0.f; }

#pragma unroll
    for (int nt = 0; nt < 8; nt++) {
        const int nrow = nt * 16 + l15;
        const float bv = b1[nrow];
        const float w20 = W2[nrow * 2 + 0];
        const float w21 = W2[nrow * 2 + 1];
#pragma unroll
        for (int t = 0; t < 2; t++)
#pragma unroll
            for (int r = 0; r < 4; r++) {
                float y = fmaxf(acc[t][nt][r] + bv, 0.f);
                o[t][r][0] += y * w20;
                o[t][r][1] += y * w21;
            }
    }

#pragma unroll
    for (int m = 1; m < 16; m <<= 1) {
#pragma unroll
        for (int t = 0; t < 2; t++)
#pragma unroll
            for (int r = 0; r < 4; r++) {
                o[t][r][0] += __shfl_xor(o[t][r][0], m, 64);
                o[t][r][1] += __shfl_xor(o[t][r][1], m, 64);
            }
    }

    if (l15 < 8) {
        const int r = l15 >> 1, c = l15 & 1;
        const float bb = c ? b2[1] : b2[0];
#pragma unroll
        for (int t = 0; t < 2; t++) {
            float v0 = (r == 0) ? o[t][0][0] : (r == 1) ? o[t][1][0] : (r == 2) ? o[t][2][0] : o[t][3][0];
            float v1 = (r == 0) ? o[t][0][1] : (r == 1) ? o[t][1][1] : (r == 2) ? o[t][2][1] : o[t][3][1];
            float v = (c ? v1 : v0) + bb;
            out[(size_t)(ebase + t * 16 + q * 4 + r) * 2 + c] = v;
        }
    }
}

// ---------------- launch ----------------

extern "C" void kernel_launch(void* const* d_in, const int* in_sizes, int n_in,
                              void* d_out, int out_size, void* d_ws, size_t ws_size,
                              hipStream_t stream)
{
    const float* nfeats = (const float*)d_in[0];
    const float* efeats = (const float*)d_in[1];
    const int*   src    = (const int*)d_in[2];
    const int*   dst    = (const int*)d_in[3];
    const float* Wm1 = (const float*)d_in[4],  *bm1 = (const float*)d_in[5];
    const float* Wa1 = (const float*)d_in[6],  *ba1 = (const float*)d_in[7];
    const float* Wm2 = (const float*)d_in[8],  *bm2 = (const float*)d_in[9];
    const float* Wa2 = (const float*)d_in[10], *ba2 = (const float*)d_in[11];
    const float* W1  = (const float*)d_in[12], *b1  = (const float*)d_in[13];
    const float* W2  = (const float*)d_in[14], *b2  = (const float*)d_in[15];
    float* out = (float*)d_out;

    char* ws = (char*)d_ws;
    float*     s     = (float*)(ws);                   // 25,600,000 B (sacc; later Q fp32 [N][128])
    int*       cnt   = (int*)(ws + 25600000);          //    200,000 B
    int*       tmp   = (int*)(ws + 25800000);          //    200,000 B
    int*       cursor= (int*)(ws + 26000000);          //    200,000 B
    int*       bsum  = (int*)(ws + 26200000);          //      1,024 B
    int*       bbase = (int*)(ws + 26201024);          //      1,024 B
    _Float16*  nf16  = (_Float16*)(ws + 26202048);     //  6,400,000 B
    int2*      pairs = (int2*)(ws + 32602048);         // 12,800,000 B (edge_id, src) per sorted slot
    int*       dsts  = (int*)(ws + 45402048);          //  6,400,000 B dst per sorted slot
    _Float16*  h1    = (_Float16*)(ws + 51802048);     // 12,800,000 B (h1; later P fp16 [N][128])
    _Float16*  Wm1t  = (_Float16*)(ws + 64602048);     //     24,576 B (msg image, K=96)
    _Float16*  Wa1t  = (_Float16*)(ws + 64626624);     //     51,200 B
    _Float16*  Wm2t  = (_Float16*)(ws + 64677824);     //     40,960 B (msg image, K=160)
    _Float16*  Wa2t  = (_Float16*)(ws + 64718784);     //     65,536 B
    _Float16*  W1t   = (_Float16*)(ws + 64784320);     //     65,536 B  -> 64,849,856

    // Tiered workspace: big_ws adds fresh h2 (sorted predictor path);
    // ef16_ws additionally adds the slot-ordered fp16 efeats table.
    const bool big_ws  = ws_size >= (size_t)77800000;
    const bool ef16_ws = ws_size >= (size_t)180100000;
    _Float16* h2 = big_ws ? (_Float16*)(ws + 64849920)   // +12,800,000 -> 77,649,920
                          : (_Float16*)(ws + 26202048);
    _Float16* efs16 = (_Float16*)(ws + 77649920);        // +102,400,000 -> 180,049,920

    hipMemsetAsync(s, 0, 25600000, stream);
    hipMemsetAsync(cnt, 0, 200000, stream);

    prep_weights<<<480, 256, 0, stream>>>(Wm1, Wa1, Wm2, Wa2, W1, Wm1t, Wa1t, Wm2t, Wa2t, W1t);
    cvt_nfeats<<<12500, 256, 0, stream>>>(nfeats, nf16);

    // counting sort of edges by dst (+ slot-ordered fp16 efeats when ws allows)
    hist_kernel<<<6250, 256, 0, stream>>>(dst, cnt);
    scan1_kernel<<<196, 256, 0, stream>>>(cnt, tmp, bsum);
    scan2_kernel<<<1, 256, 0, stream>>>(bsum, bbase);
    scan3_kernel<<<196, 256, 0, stream>>>(cnt, tmp, bbase, cursor);
    if (ef16_ws)
        scatter_kernel_ef<<<6250, 256, 0, stream>>>(src, dst, efeats, cursor, pairs, dsts, efs16);
    else
        scatter_kernel<<<6250, 256, 0, stream>>>(src, dst, cursor, pairs, dsts);

    // layer 1 (LDS 24576 B)
    if (ef16_ws)
        msg_kernel_sorted<64, 4, true><<<12500, 256, 0, stream>>>(nf16, efeats, efs16, pairs, dsts, Wm1t, bm1, s);
    else
        msg_kernel_sorted<64, 4, false><<<12500, 256, 0, stream>>>(nf16, efeats, nullptr, pairs, dsts, Wm1t, bm1, s);
    apply_kernel<64, false, 200><<<391, 256, 0, stream>>>(nf16, s, cnt, Wa1t, ba1, h1);

    // layer 2 (LDS 40960 B)
    hipMemsetAsync(s, 0, 25600000, stream);
    if (ef16_ws)
        msg_kernel_sorted<128, 4, true><<<12500, 256, 0, stream>>>(h1, efeats, efs16, pairs, dsts, Wm2t, bm2, s);
    else
        msg_kernel_sorted<128, 4, false><<<12500, 256, 0, stream>>>(h1, efeats, nullptr, pairs, dsts, Wm2t, bm2, s);
    apply_kernel<128, true, 256><<<391, 256, 0, stream>>>(h1, s, cnt, Wa2t, ba2, h2);

    // predictor
    if (big_ws) {
        _Float16* P = h1;   // h1 dead after apply2
        float*    Q = s;    // sacc dead after apply2
        node_pq_kernel<<<391, 256, 0, stream>>>(h2, W1t, b1, P, Q);
        pred_elem_kernel<<<6250, 256, 0, stream>>>(P, Q, pairs, dsts, W2, b2, out);
    } else {
        pred_kernel<<<12500, 256, 0, stream>>>(h2, src, dst, W1t, b1, W2, b2, out);
    }
}